// Round 3
// baseline (2075.644 us; speedup 1.0000x reference)
//
#include <hip/hip_runtime.h>

// Problem constants (from setup_inputs)
#define NB      512          // number of blocks
#define NSAMP   2101312L     // y samples per pol
#define SOUT    2048         // downsampled symbols per block per pol
#define LOFF    12           // (L-1)/2 for h_est L=25
#define NJ      4072         // N - L + 1
#define CHUNK   1024         // symbols per chunk
#define NCHUNK  2
#define XSTG    1056         // staged sample-pairs per pol per chunk (1024 + 32)

#define OUTY_OFF   0
#define OUTQ_OFF   4194304L
#define OUTVAR_OFF (4194304L + 67108864L)

__global__ __launch_bounds__(512, 4)
void vae_elbo_kernel(const float* __restrict__ y,
                     const float* __restrict__ taps,   // (2,2,65,2)
                     const float* __restrict__ h_est,  // (2,2,2,25)
                     const float* __restrict__ amp,    // (16)
                     const float* __restrict__ p_sym,  // (16)
                     const float* __restrict__ nsig,   // (1)
                     float* __restrict__ out)
{
    const int k   = blockIdx.x;
    const int tid = threadIdx.x;
    const long Bk = (long)k * 4096;   // window base sample index

    float* const out_y    = out + OUTY_OFF;
    float* const out_q    = out + OUTQ_OFF;
    float* const out_var  = out + OUTVAR_OFF;
    float* const out_loss = out + OUTVAR_OFF + 2;

    // Polyphase staging as float2 (re,im): b64 LDS reads, 8B lane stride (free).
    __shared__ float2 xe[2][XSTG];    // even samples, per input pol
    __shared__ float2 xo[2][XSTG];    // odd samples
    __shared__ float2 EL[2][SOUT];    // (E0, E1) per output pol per symbol
    __shared__ float  Vlo[2][LOFF], Vhi[2][LOFF];
    __shared__ float  red[8][12];

    const float sg = nsig[0];
    const float inv2s2 = 1.0f / (2.0f * sg * sg);

    float kl_acc = 0.0f;
    float vt0 = 0.0f, vt1 = 0.0f;

    // Demap one 16-way softmax: computes q, accumulates E/V/KL, stores q.
    // No persistent q array -> only z[16] live (register-friendly).
    auto demap16 = [&](float yh, float* qdst, float& Eo, float& Vs, float& klp,
                       bool doKL) {
        float z[16];
        float zm = -3.0e38f;
        #pragma unroll
        for (int c = 0; c < 16; ++c) {
            float d = yh - amp[c];            // amp[c]: uniform -> SGPR
            z[c] = -d * d * inv2s2;
            zm = fmaxf(zm, z[c]);
        }
        float se = 0.f;
        #pragma unroll
        for (int c = 0; c < 16; ++c) { z[c] = __expf(z[c] - zm); se += z[c]; }
        const float inv = 1.0f / se;
        #pragma unroll
        for (int c = 0; c < 16; ++c) {
            float q = z[c] * inv;
            z[c] = q;
            float t = q * amp[c];
            Eo += t;
            Vs = fmaf(t, amp[c], Vs);
            if (doKL) {
                const float ip = 1.0f / p_sym[c];   // uniform, hoisted
                klp += q * __logf(fmaf(q, ip, 1e-14f));
            }
        }
        #pragma unroll
        for (int w = 0; w < 4; ++w)
            ((float4*)qdst)[w] = make_float4(z[4*w], z[4*w+1], z[4*w+2], z[4*w+3]);
    };

    // ---------------- Phase 1: FIR conv + demap + moments + q store ----------------
    #pragma unroll 1
    for (int cn = 0; cn < NCHUNK; ++cn) {
        const int s0 = cn * CHUNK;
        __syncthreads();   // prior chunk's xe/xo reads complete
        {
            const float4* y4 = (const float4*)y;  // (re[2u],im[2u],re[2u+1],im[2u+1])
            #pragma unroll
            for (int it = 0; it < 5; ++it) {
                int idx = tid + it * 512;
                if (idx < 2 * XSTG) {
                    int i = (idx >= XSTG) ? 1 : 0;
                    int u = idx - i * XSTG;
                    float4 v = y4[(((long)i * NSAMP + Bk) >> 1) + s0 + u];
                    xe[i][u] = make_float2(v.x, v.y);
                    xo[i][u] = make_float2(v.z, v.w);
                }
            }
        }
        __syncthreads();

        // Two symbols per thread, spaced by 512 (conflict-free b64 windows):
        // A: within-chunk tid, B: tid+512.
        float arA0=0.f, aiA0=0.f, arA1=0.f, aiA1=0.f;
        float arB0=0.f, aiB0=0.f, arB1=0.f, aiB1=0.f;
        #pragma unroll
        for (int i = 0; i < 2; ++i) {
            const float* tA = taps + i * 130;         // out-pol 0, uniform -> s_load
            const float* tB = taps + 260 + i * 130;   // out-pol 1
            #pragma unroll
            for (int m = 0; m <= 32; ++m) {           // even taps l=2m
                float2 ea = xe[i][tid + m];
                float2 eb = xe[i][tid + 512 + m];
                float wr = tA[4*m], wi = tA[4*m + 1];
                arA0 = fmaf(ea.x, wr, arA0); arA0 = fmaf(-ea.y, wi, arA0);
                aiA0 = fmaf(ea.x, wi, aiA0); aiA0 = fmaf( ea.y, wr, aiA0);
                arB0 = fmaf(eb.x, wr, arB0); arB0 = fmaf(-eb.y, wi, arB0);
                aiB0 = fmaf(eb.x, wi, aiB0); aiB0 = fmaf( eb.y, wr, aiB0);
                wr = tB[4*m]; wi = tB[4*m + 1];
                arA1 = fmaf(ea.x, wr, arA1); arA1 = fmaf(-ea.y, wi, arA1);
                aiA1 = fmaf(ea.x, wi, aiA1); aiA1 = fmaf( ea.y, wr, aiA1);
                arB1 = fmaf(eb.x, wr, arB1); arB1 = fmaf(-eb.y, wi, arB1);
                aiB1 = fmaf(eb.x, wi, aiB1); aiB1 = fmaf( eb.y, wr, aiB1);
            }
            #pragma unroll
            for (int m = 0; m < 32; ++m) {            // odd taps l=2m+1
                float2 oa = xo[i][tid + m];
                float2 ob = xo[i][tid + 512 + m];
                float wr = tA[4*m + 2], wi = tA[4*m + 3];
                arA0 = fmaf(oa.x, wr, arA0); arA0 = fmaf(-oa.y, wi, arA0);
                aiA0 = fmaf(oa.x, wi, aiA0); aiA0 = fmaf( oa.y, wr, aiA0);
                arB0 = fmaf(ob.x, wr, arB0); arB0 = fmaf(-ob.y, wi, arB0);
                aiB0 = fmaf(ob.x, wi, aiB0); aiB0 = fmaf( ob.y, wr, aiB0);
                wr = tB[4*m + 2]; wi = tB[4*m + 3];
                arA1 = fmaf(oa.x, wr, arA1); arA1 = fmaf(-oa.y, wi, arA1);
                aiA1 = fmaf(oa.x, wi, aiA1); aiA1 = fmaf( oa.y, wr, aiA1);
                arB1 = fmaf(ob.x, wr, arB1); arB1 = fmaf(-ob.y, wi, arB1);
                aiB1 = fmaf(ob.x, wi, aiB1); aiB1 = fmaf( ob.y, wr, aiB1);
            }
        }

        #pragma unroll
        for (int j = 0; j < 2; ++j) {
            const int sgb = s0 + tid + j * 512;   // global symbol index in block
            const bool doKL = (sgb >= LOFF) && (sgb < SOUT - LOFF);
            #pragma unroll
            for (int o = 0; o < 2; ++o) {
                const float yhr = o ? (j ? arB1 : arA1) : (j ? arB0 : arA0);
                const float yhi = o ? (j ? aiB1 : aiA1) : (j ? aiB0 : aiA0);
                float E0 = 0.f, E1 = 0.f, Vs = 0.f, klp = 0.f;
                const long gy = ((long)(o * NB + k)) * SOUT + sgb;
                demap16(yhr, out_q + gy * 32,      E0, Vs, klp, doKL);
                demap16(yhi, out_q + gy * 32 + 16, E1, Vs, klp, doKL);
                Vs -= E0 * E0 + E1 * E1;

                EL[o][sgb] = make_float2(E0, E1);
                if (o == 0) vt0 += Vs; else vt1 += Vs;
                if (sgb < LOFF)          Vlo[o][sgb] = Vs;
                if (sgb >= SOUT - LOFF)  Vhi[o][sgb - (SOUT - LOFF)] = Vs;
                kl_acc += klp;

                ((float2*)out_y)[gy] = make_float2(yhr, yhi);
            }
        }
    }
    __syncthreads();

    // ---------------- Phase 2: D = conv(upsampled E, h)[24:4096), C terms ----------
    float sy2[2] = {0.f, 0.f}, syd[2] = {0.f, 0.f}, sd2[2] = {0.f, 0.f};
    #pragma unroll 1
    for (int r = 0; r < 4; ++r) {
        const int t2 = tid + r * 512;
        if (t2 < SOUT - LOFF) {          // t2 in [0, 2036)
            // parity 0 output j=2*t2, parity 1 output j=2*t2+1: shared EL window
            float dr0e=0.f, di0e=0.f, dr1e=0.f, di1e=0.f;   // even parity, pols 0/1
            float dr0o=0.f, di0o=0.f, dr1o=0.f, di1o=0.f;   // odd parity
            #pragma unroll
            for (int i = 0; i < 2; ++i) {
                #pragma unroll
                for (int m = 0; m <= 12; ++m) {
                    const float2 el = EL[i][t2 + 12 - m];
                    {   // even parity tap l=2m
                        const int l = 2 * m;
                        float h0r = h_est[((0*2 + i)*2 + 0)*25 + l];
                        float h0i = h_est[((0*2 + i)*2 + 1)*25 + l];
                        float h1r = h_est[((1*2 + i)*2 + 0)*25 + l];
                        float h1i = h_est[((1*2 + i)*2 + 1)*25 + l];
                        dr0e = fmaf(el.x, h0r, dr0e); dr0e = fmaf(-el.y, h0i, dr0e);
                        di0e = fmaf(el.x, h0i, di0e); di0e = fmaf( el.y, h0r, di0e);
                        dr1e = fmaf(el.x, h1r, dr1e); dr1e = fmaf(-el.y, h1i, dr1e);
                        di1e = fmaf(el.x, h1i, di1e); di1e = fmaf( el.y, h1r, di1e);
                    }
                    if (m < 12) {   // odd parity tap l=2m+1
                        const int l = 2 * m + 1;
                        float h0r = h_est[((0*2 + i)*2 + 0)*25 + l];
                        float h0i = h_est[((0*2 + i)*2 + 1)*25 + l];
                        float h1r = h_est[((1*2 + i)*2 + 0)*25 + l];
                        float h1i = h_est[((1*2 + i)*2 + 1)*25 + l];
                        dr0o = fmaf(el.x, h0r, dr0o); dr0o = fmaf(-el.y, h0i, dr0o);
                        di0o = fmaf(el.x, h0i, di0o); di0o = fmaf( el.y, h0r, di0o);
                        dr1o = fmaf(el.x, h1r, dr1o); dr1o = fmaf(-el.y, h1i, dr1o);
                        di1o = fmaf(el.x, h1i, di1o); di1o = fmaf( el.y, h1r, di1o);
                    }
                }
            }
            // y at j = 2*t2, 2*t2+1 for both pols: one float4 each (16B aligned)
            float4 yv = *(const float4*)&y[(Bk + 44 + 2*t2) * 2];
            sy2[0] += yv.x*yv.x + yv.y*yv.y + yv.z*yv.z + yv.w*yv.w;
            syd[0] += yv.x*dr0e + yv.y*di0e + yv.z*dr0o + yv.w*di0o;
            sd2[0] += dr0e*dr0e + di0e*di0e + dr0o*dr0o + di0o*di0o;
            yv = *(const float4*)&y[(NSAMP + Bk + 44 + 2*t2) * 2];
            sy2[1] += yv.x*yv.x + yv.y*yv.y + yv.z*yv.z + yv.w*yv.w;
            syd[1] += yv.x*dr1e + yv.y*di1e + yv.z*dr1o + yv.w*di1o;
            sd2[1] += dr1e*dr1e + di1e*di1e + dr1o*dr1o + di1o*di1o;
        }
    }

    // ---------------- Reduction + finalize ----------------
    float vals[9] = {kl_acc, vt0, vt1, sy2[0], sy2[1], syd[0], syd[1], sd2[0], sd2[1]};
    #pragma unroll
    for (int d = 32; d >= 1; d >>= 1) {
        #pragma unroll
        for (int v = 0; v < 9; ++v)
            vals[v] += __shfl_down(vals[v], (unsigned)d, 64);
    }
    const int wv = tid >> 6;
    if ((tid & 63) == 0) {
        #pragma unroll
        for (int v = 0; v < 9; ++v) red[wv][v] = vals[v];
    }
    __syncthreads();

    if (tid == 0) {
        float tot[9];
        #pragma unroll
        for (int v = 0; v < 9; ++v) {
            float t = 0.f;
            #pragma unroll
            for (int w = 0; w < 8; ++w) t += red[w][v];
            tot[v] = t;
        }
        // E term: Wsum[i][l] = Vtot - (excluded prefix) - (excluded suffix)
        float Et0 = 0.f, Et1 = 0.f;
        #pragma unroll
        for (int i = 0; i < 2; ++i) {
            const float Vt = (i == 0) ? tot[1] : tot[2];
            float plo[13], phi[13];
            plo[0] = 0.f; phi[0] = 0.f;
            #pragma unroll
            for (int t = 0; t < 12; ++t) {
                plo[t + 1] = plo[t] + Vlo[i][t];
                phi[t + 1] = phi[t] + Vhi[i][11 - t];
            }
            #pragma unroll
            for (int l = 0; l < 25; ++l) {
                int lo, hi;
                if ((l & 1) == 0) { lo = 12 - l / 2;     hi = l / 2; }
                else             { lo = (25 - l) / 2;    hi = (l - 1) / 2; }
                const float ws = Vt - plo[lo] - phi[hi];
                const float h00 = h_est[((0*2 + i)*2 + 0)*25 + l];
                const float h01 = h_est[((0*2 + i)*2 + 1)*25 + l];
                const float h10 = h_est[((1*2 + i)*2 + 0)*25 + l];
                const float h11 = h_est[((1*2 + i)*2 + 1)*25 + l];
                Et0 += (h00 * h00 + h01 * h01) * ws;
                Et1 += (h10 * h10 + h11 * h11) * ws;
            }
        }
        const float C0 = tot[3] - 2.0f * tot[5] + tot[7] + Et0;
        const float C1 = tot[4] - 2.0f * tot[6] + tot[8] + Et1;
        const float loss = tot[0] + 4072.0f * (logf(C0 + 1e-8f) + logf(C1 + 1e-8f));
        out_loss[k] = loss;
        if (k == NB - 1) {
            out_var[0] = C0 / 4072.0f;
            out_var[1] = C1 / 4072.0f;
        }
    }
}

extern "C" void kernel_launch(void* const* d_in, const int* in_sizes, int n_in,
                              void* d_out, int out_size, void* d_ws, size_t ws_size,
                              hipStream_t stream) {
    const float* y     = (const float*)d_in[0];
    const float* taps  = (const float*)d_in[1];
    const float* h_est = (const float*)d_in[2];
    const float* amp   = (const float*)d_in[3];
    const float* p_sym = (const float*)d_in[4];
    const float* nsig  = (const float*)d_in[5];
    (void)in_sizes; (void)n_in; (void)out_size; (void)d_ws; (void)ws_size;

    vae_elbo_kernel<<<NB, 512, 0, stream>>>(y, taps, h_est, amp, p_sym, nsig,
                                            (float*)d_out);
}